// Round 16
// baseline (474.321 us; speedup 1.0000x reference)
//
#include <hip/hip_runtime.h>

#define N_NODES 100000
#define N_EDGES 3200000
#define N_GRAPHS 4096
#define IN_DIM 74
#define HID 64
#define MLP_HID 128

#define BKT_NODES 128                 // nodes per bucket
#define NBUCKET ((N_NODES + BKT_NODES - 1) / BKT_NODES)   // 782
#define BUCKET_CAP 8192               // edges capacity per bucket (mean ~4096)
#define NBLK 256                      // split blocks (long per-bucket runs)
#define SPLIT_THREADS 1024            // fat blocks for occupancy
#define CHUNK ((N_EDGES + NBLK - 1) / NBLK)               // 12500 (N_EDGES = NBLK*CHUNK exactly)

// prep'd weight layout sizes (bf16, transposed [feat][k], padded stride)
#define STRIDE0 104                   // layer0: KPAD=96, stride 104 (208B rows, 16B-aligned)
#define STRIDE12 72                   // layers 1,2: KPAD=64, stride 72 (144B rows, 16B-aligned)
#define SZ0 (64 * STRIDE0)
#define SZ12 (64 * STRIDE12)

typedef __attribute__((ext_vector_type(8))) short bf16x8;
typedef __attribute__((ext_vector_type(4))) float f32x4;

__device__ __forceinline__ unsigned short f32_to_bf16_rne(float f) {
    unsigned u = __float_as_uint(f);
    unsigned r = (u + 0x7FFFu + ((u >> 16) & 1u)) >> 16;
    return (unsigned short)r;
}
__device__ __forceinline__ float bf16u_f(unsigned short u) {
    return __uint_as_float((unsigned)u << 16);
}

// accumulate 8 int8 feats (one uint2) scaled by s into a0..a7
#define ACC8(v, s) do { \
    a0 = fmaf((float)((int)((v).x << 24) >> 24), (s), a0); \
    a1 = fmaf((float)((int)((v).x << 16) >> 24), (s), a1); \
    a2 = fmaf((float)((int)((v).x <<  8) >> 24), (s), a2); \
    a3 = fmaf((float)((int)(v).x        >> 24), (s), a3); \
    a4 = fmaf((float)((int)((v).y << 24) >> 24), (s), a4); \
    a5 = fmaf((float)((int)((v).y << 16) >> 24), (s), a5); \
    a6 = fmaf((float)((int)((v).y <<  8) >> 24), (s), a6); \
    a7 = fmaf((float)((int)(v).y        >> 24), (s), a7); \
} while (0)

// ---- one-time weight prep: Wt[l][feat][k] = bf16(W_l[k][feat]), zero-padded.
__global__ void prep_wt_kernel(const float* __restrict__ W0, const float* __restrict__ R0,
                               const float* __restrict__ W1, const float* __restrict__ R1,
                               const float* __restrict__ W2, const float* __restrict__ R2,
                               unsigned short* __restrict__ wtbuf) {
    const float* srcs[6] = {W0, R0, W1, R1, W2, R2};
    int id = blockIdx.x;
    int l = id >> 1, isR = id & 1;
    const float* src = srcs[id];
    int IN = (l == 0) ? IN_DIM : HID;
    int STRIDE = (l == 0) ? STRIDE0 : STRIDE12;
    int base = (l == 0 ? 0 : 2 * SZ0 + (l - 1) * 2 * SZ12) + isR * (l == 0 ? SZ0 : SZ12);
    int total = 64 * STRIDE;
    for (int i = threadIdx.x; i < total; i += 256) {
        int n = i / STRIDE, k = i - n * STRIDE;
        wtbuf[base + i] = (k < IN) ? f32_to_bf16_rne(src[k * HID + n]) : 0;
    }
}

// ---- projection via MFMA: xq(i8, split-half layout, per-node scale) = x@W ;
// res(bf16) = relu(x@R+rb). LDS holds only the x tile; W/R read from global
// (19 KB, L1-resident). xq layout: half h = dwords [h*8, h*8+8) of the row,
// stored at xq[h*N_NODES*8 + node*8 + d]; dword c holds feats {c,+16,+32,+48}.
template<int IN, int KPAD, int STRIDE, bool BF16IN>
__launch_bounds__(256)
__global__ void proj_mfma_kernel(const void* __restrict__ x,
                                 const unsigned short* __restrict__ wt_layer, // W then R
                                 const float* __restrict__ rb,
                                 unsigned* __restrict__ xq,       // split-half layout
                                 float* __restrict__ xscale,      // 1 f32/node
                                 unsigned short* __restrict__ resb,
                                 int n_nodes) {
    __shared__ __align__(16) unsigned short xs[64 * STRIDE];
    int n0 = blockIdx.x * 64;
    int tid = threadIdx.x;

    if (!BF16IN) {
        const float* xf = (const float*)x;
        for (int i = tid; i < 64 * STRIDE; i += 256) {
            int row = i / STRIDE, col = i - row * STRIDE;
            int n = n0 + row;
            float v = (col < IN && n < n_nodes) ? xf[(long)n * IN + col] : 0.f;
            xs[i] = f32_to_bf16_rne(v);
        }
    } else {
        const uint4* xb = (const uint4*)x;
        for (int i = tid; i < 64 * 8; i += 256) {
            int row = i >> 3, c8 = (i & 7) << 3;
            int n = n0 + row;
            uint4 v = make_uint4(0, 0, 0, 0);
            if (n < n_nodes) v = xb[(long)n * 8 + (i & 7)];
            *reinterpret_cast<uint4*>(&xs[row * STRIDE + c8]) = v;
        }
    }
    __syncthreads();

    int w = tid >> 6, lane = tid & 63;
    int nb = w * 16;
    int rc = lane & 15;        // A row / B col / D col
    int kg = lane >> 4;        // k-chunk of 8

    f32x4 accW[4], accR[4];
    #pragma unroll
    for (int fg = 0; fg < 4; ++fg) { accW[fg] = {0.f, 0.f, 0.f, 0.f}; accR[fg] = {0.f, 0.f, 0.f, 0.f}; }

    const unsigned short* wt = wt_layer;                 // [feat][k] bf16
    const unsigned short* rt = wt_layer + 64 * STRIDE;

    #pragma unroll
    for (int ks = 0; ks < KPAD / 32; ++ks) {
        int k0 = ks * 32 + kg * 8;
        bf16x8 a = *reinterpret_cast<const bf16x8*>(&xs[(nb + rc) * STRIDE + k0]);
        #pragma unroll
        for (int fg = 0; fg < 4; ++fg) {
            bf16x8 bw = *reinterpret_cast<const bf16x8*>(&wt[(fg * 16 + rc) * STRIDE + k0]);
            accW[fg] = __builtin_amdgcn_mfma_f32_16x16x32_bf16(a, bw, accW[fg], 0, 0, 0);
            bf16x8 br = *reinterpret_cast<const bf16x8*>(&rt[(fg * 16 + rc) * STRIDE + k0]);
            accR[fg] = __builtin_amdgcn_mfma_f32_16x16x32_bf16(a, br, accR[fg], 0, 0, 0);
        }
    }

    // D: col = lane&15, row = (lane>>4)*4 + reg; quarter shares the node.
    unsigned* xqh = xq + (size_t)(rc >> 3) * N_NODES * 8;   // half table
    int d = rc & 7;                                         // dword within half
    #pragma unroll
    for (int r = 0; r < 4; ++r) {
        float m = fmaxf(fmaxf(fabsf(accW[0][r]), fabsf(accW[1][r])),
                        fmaxf(fabsf(accW[2][r]), fabsf(accW[3][r])));
        m = fmaxf(m, __shfl_xor(m, 1, 64));
        m = fmaxf(m, __shfl_xor(m, 2, 64));
        m = fmaxf(m, __shfl_xor(m, 4, 64));
        m = fmaxf(m, __shfl_xor(m, 8, 64));
        float inv = (m > 0.f) ? 127.f / m : 0.f;
        int node = n0 + nb + kg * 4 + r;
        if (node < n_nodes) {
            unsigned pack = 0;
            #pragma unroll
            for (int fg = 0; fg < 4; ++fg) {
                int qv = (int)rintf(accW[fg][r] * inv);
                pack |= ((unsigned)(qv & 0xFF)) << (8 * fg);
            }
            xqh[(long)node * 8 + d] = pack;
            if (rc == 0) xscale[node] = m * (1.f / 127.f);
        }
    }
    #pragma unroll
    for (int fg = 0; fg < 4; ++fg) {
        int feat = fg * 16 + rc;
        float rbv = rb[feat];
        #pragma unroll
        for (int r = 0; r < 4; ++r) {
            int node = n0 + nb + kg * 4 + r;
            if (node < n_nodes)
                resb[(long)node * HID + feat] = f32_to_bf16_rne(fmaxf(accR[fg][r] + rbv, 0.f));
        }
    }
}

// ---- split pass 1: per-block LDS histogram of dst buckets (int4 loads)
__launch_bounds__(SPLIT_THREADS)
__global__ void split_hist_kernel(const int* __restrict__ dst,
                                  int* __restrict__ blockHist /*[NBUCKET][NBLK]*/) {
    __shared__ int h[NBUCKET];
    int blk = blockIdx.x, tid = threadIdx.x;
    for (int i = tid; i < NBUCKET; i += SPLIT_THREADS) h[i] = 0;
    __syncthreads();
    int lo = blk * CHUNK;                      // CHUNK % 4 == 0, 16B-aligned
    for (int e = lo + tid * 4; e < lo + CHUNK; e += SPLIT_THREADS * 4) {
        int4 d4 = *reinterpret_cast<const int4*>(&dst[e]);
        atomicAdd(&h[d4.x >> 7], 1);
        atomicAdd(&h[d4.y >> 7], 1);
        atomicAdd(&h[d4.z >> 7], 1);
        atomicAdd(&h[d4.w >> 7], 1);
    }
    __syncthreads();
    for (int i = tid; i < NBUCKET; i += SPLIT_THREADS)
        blockHist[i * NBLK + blk] = h[i];
}

// ---- split pass 2: per-bucket exclusive scan over the NBLK block counts.
__launch_bounds__(NBLK)
__global__ void split_scan_kernel(int* __restrict__ blockHist,
                                  int* __restrict__ cursor) {
    __shared__ int s[NBLK];
    int bkt = blockIdx.x, tid = threadIdx.x;
    int v = blockHist[bkt * NBLK + tid];
    s[tid] = v;
    __syncthreads();
    for (int off = 1; off < NBLK; off <<= 1) {
        int t = (tid >= off) ? s[tid - off] : 0;
        __syncthreads();
        s[tid] += t;
        __syncthreads();
    }
    blockHist[bkt * NBLK + tid] = bkt * BUCKET_CAP + s[tid] - v;   // exclusive
    if (tid == NBLK - 1) cursor[bkt] = bkt * BUCKET_CAP + s[tid]; // total end
}

// ---- split pass 3: scatter to exact positions (LDS cursors; int4 loads)
__launch_bounds__(SPLIT_THREADS)
__global__ void split_scatter_kernel(const int* __restrict__ src,
                                     const int* __restrict__ dst,
                                     const int* __restrict__ blockHist,
                                     unsigned* __restrict__ pairs) {
    __shared__ int cur[NBUCKET];
    int blk = blockIdx.x, tid = threadIdx.x;
    for (int i = tid; i < NBUCKET; i += SPLIT_THREADS)
        cur[i] = blockHist[i * NBLK + blk];
    __syncthreads();
    int lo = blk * CHUNK;
    for (int e = lo + tid * 4; e < lo + CHUNK; e += SPLIT_THREADS * 4) {
        int4 d4 = *reinterpret_cast<const int4*>(&dst[e]);
        int4 s4 = *reinterpret_cast<const int4*>(&src[e]);
        int p0 = atomicAdd(&cur[d4.x >> 7], 1);
        pairs[p0] = (unsigned)s4.x | ((unsigned)(d4.x & (BKT_NODES - 1)) << 17);
        int p1 = atomicAdd(&cur[d4.y >> 7], 1);
        pairs[p1] = (unsigned)s4.y | ((unsigned)(d4.y & (BKT_NODES - 1)) << 17);
        int p2 = atomicAdd(&cur[d4.z >> 7], 1);
        pairs[p2] = (unsigned)s4.z | ((unsigned)(d4.z & (BKT_NODES - 1)) << 17);
        int p3 = atomicAdd(&cur[d4.w >> 7], 1);
        pairs[p3] = (unsigned)s4.w | ((unsigned)(d4.w & (BKT_NODES - 1)) << 17);
    }
}

// ---- per-bucket LDS counting sort -> src sorted by dst_local; row_start/row_deg
__launch_bounds__(256)
__global__ void bucket_sort_kernel(unsigned* __restrict__ pairs,
                                   const int* __restrict__ cursor,
                                   int* __restrict__ row_start,
                                   int* __restrict__ row_deg) {
    __shared__ unsigned stage[BUCKET_CAP];   // 32 KB
    __shared__ int hist[BKT_NODES];
    __shared__ int offs[BKT_NODES];
    __shared__ int cur[BKT_NODES];
    int bkt = blockIdx.x;
    int tid = threadIdx.x;
    int base = bkt * BUCKET_CAP;
    int cnt = cursor[bkt] - base;

    for (int i = tid; i < BKT_NODES; i += 256) hist[i] = 0;
    __syncthreads();
    for (int e = tid; e < cnt; e += 256) {
        unsigned p = pairs[base + e];
        stage[e] = p;
        atomicAdd(&hist[p >> 17], 1);
    }
    __syncthreads();
    if (tid < BKT_NODES) offs[tid] = hist[tid];
    __syncthreads();
    for (int s = 1; s < BKT_NODES; s <<= 1) {
        int v = (tid < BKT_NODES && tid >= s) ? offs[tid - s] : 0;
        __syncthreads();
        if (tid < BKT_NODES) offs[tid] += v;
        __syncthreads();
    }
    if (tid < BKT_NODES) {
        int ex = offs[tid] - hist[tid];
        cur[tid] = ex;
        int node = bkt * BKT_NODES + tid;
        if (node < N_NODES) {
            row_start[node] = base + ex;
            row_deg[node] = hist[tid];
        }
    }
    __syncthreads();
    for (int e = tid; e < cnt; e += 256) {
        unsigned p = stage[e];
        int pos = atomicAdd(&cur[p >> 17], 1);
        pairs[base + pos] = p & 0x1FFFF;   // store src only
    }
}

// ---- gather aggregation over ONE 3.2 MB half-table (L2-resident per pass).
// One wave per node; 16 edges per step (quarter of 4 lanes per edge, uint2 =
// 32B half-row). fbase = half*8. Writes feats {fbase+2c2+blk*16, +1}.
__launch_bounds__(256)
__global__ void gather_half_kernel(const uint2* __restrict__ xq2h,  // 4 uint2/node
                                   const float* __restrict__ xscale,
                                   const int* __restrict__ row_start,
                                   const int* __restrict__ row_deg,
                                   const unsigned* __restrict__ csr_src,
                                   const float* __restrict__ b,
                                   const unsigned short* __restrict__ resb,
                                   unsigned short* __restrict__ xoutb,
                                   int fbase, int n_nodes) {
    int wid = (blockIdx.x * blockDim.x + threadIdx.x) >> 6;
    int lane = threadIdx.x & 63;
    if (wid >= n_nodes) return;
    int g = lane >> 2;        // edge slot 0..15
    int c2 = lane & 3;        // uint2 index within half-row
    int start = row_start[wid];
    int end = start + row_deg[wid];
    float a0 = 0.f, a1 = 0.f, a2 = 0.f, a3 = 0.f;
    float a4 = 0.f, a5 = 0.f, a6 = 0.f, a7 = 0.f;
    int e = start;
    for (; e + 16 <= end; e += 16) {
        unsigned s = csr_src[e + g];
        uint2 v = xq2h[(size_t)s * 4 + c2]; float cs = xscale[s];
        ACC8(v, cs);
    }
    if (e < end && g < end - e) {
        unsigned s = csr_src[e + g];
        uint2 v = xq2h[(size_t)s * 4 + c2]; float cs = xscale[s];
        ACC8(v, cs);
    }
    a0 += __shfl_xor(a0, 4, 64); a0 += __shfl_xor(a0, 8, 64); a0 += __shfl_xor(a0, 16, 64); a0 += __shfl_xor(a0, 32, 64);
    a1 += __shfl_xor(a1, 4, 64); a1 += __shfl_xor(a1, 8, 64); a1 += __shfl_xor(a1, 16, 64); a1 += __shfl_xor(a1, 32, 64);
    a2 += __shfl_xor(a2, 4, 64); a2 += __shfl_xor(a2, 8, 64); a2 += __shfl_xor(a2, 16, 64); a2 += __shfl_xor(a2, 32, 64);
    a3 += __shfl_xor(a3, 4, 64); a3 += __shfl_xor(a3, 8, 64); a3 += __shfl_xor(a3, 16, 64); a3 += __shfl_xor(a3, 32, 64);
    a4 += __shfl_xor(a4, 4, 64); a4 += __shfl_xor(a4, 8, 64); a4 += __shfl_xor(a4, 16, 64); a4 += __shfl_xor(a4, 32, 64);
    a5 += __shfl_xor(a5, 4, 64); a5 += __shfl_xor(a5, 8, 64); a5 += __shfl_xor(a5, 16, 64); a5 += __shfl_xor(a5, 32, 64);
    a6 += __shfl_xor(a6, 4, 64); a6 += __shfl_xor(a6, 8, 64); a6 += __shfl_xor(a6, 16, 64); a6 += __shfl_xor(a6, 32, 64);
    a7 += __shfl_xor(a7, 4, 64); a7 += __shfl_xor(a7, 8, 64); a7 += __shfl_xor(a7, 16, 64); a7 += __shfl_xor(a7, 32, 64);
    if (g == 0) {
        long o = (long)wid * HID;
        int f = fbase + 2 * c2;
        #pragma unroll
        for (int blk4 = 0; blk4 < 4; ++blk4) {
            int ff = f + blk4 * 16;
            float lo_a = (blk4 == 0) ? a0 : (blk4 == 1) ? a1 : (blk4 == 2) ? a2 : a3;
            float hi_a = (blk4 == 0) ? a4 : (blk4 == 1) ? a5 : (blk4 == 2) ? a6 : a7;
            float2 bv = *reinterpret_cast<const float2*>(&b[ff]);
            unsigned rv = *reinterpret_cast<const unsigned*>(&resb[o + ff]);
            float w0 = fmaxf(lo_a + bv.x, 0.f) + __uint_as_float(rv << 16);
            float w1 = fmaxf(hi_a + bv.y, 0.f) + __uint_as_float(rv & 0xFFFF0000u);
            unsigned ov = (unsigned)f32_to_bf16_rne(w0) | ((unsigned)f32_to_bf16_rne(w1) << 16);
            *reinterpret_cast<unsigned*>(&xoutb[o + ff]) = ov;
        }
    }
}

// ---- pooling gather over bf16 x: one wave/graph, binary search range
__global__ void pool_gather_kernel(const unsigned short* __restrict__ x,
                                   const int* __restrict__ gid,
                                   float* __restrict__ g,
                                   int n_graphs) {
    int wid = (blockIdx.x * blockDim.x + threadIdx.x) >> 6;
    int lane = threadIdx.x & 63;
    if (wid >= n_graphs) return;
    int lo = 0, hi = N_NODES;
    while (lo < hi) { int mid = (lo + hi) >> 1; if (gid[mid] < wid) lo = mid + 1; else hi = mid; }
    int start = lo;
    hi = N_NODES;
    while (lo < hi) { int mid = (lo + hi) >> 1; if (gid[mid] < wid + 1) lo = mid + 1; else hi = mid; }
    int end = lo;
    float acc = 0.f;
    for (int n = start; n < end; ++n)
        acc += bf16u_f(x[(long)n * HID + lane]);
    g[(long)wid * HID + lane] = acc;
}

// ---- MLP: one wave per graph. out = relu(g@Wm1+bm1) @ Wm2 + bm2
__global__ void mlp_kernel(const float* __restrict__ g,
                           const float* __restrict__ Wm1,
                           const float* __restrict__ bm1,
                           const float* __restrict__ Wm2,
                           const float* __restrict__ bm2,
                           float* __restrict__ out,
                           int n_graphs) {
    int wid = (blockIdx.x * blockDim.x + threadIdx.x) >> 6;
    int lane = threadIdx.x & 63;
    if (wid >= n_graphs) return;
    const float* gr = g + (long)wid * HID;
    float h0 = bm1[lane];
    float h1 = bm1[lane + 64];
    for (int k = 0; k < HID; ++k) {
        float gv = gr[k];
        h0 += gv * Wm1[k * MLP_HID + lane];
        h1 += gv * Wm1[k * MLP_HID + lane + 64];
    }
    float part = fmaxf(h0, 0.f) * Wm2[lane] + fmaxf(h1, 0.f) * Wm2[lane + 64];
    #pragma unroll
    for (int off = 32; off > 0; off >>= 1)
        part += __shfl_down(part, off, 64);
    if (lane == 0) out[wid] = part + bm2[0];
}

extern "C" void kernel_launch(void* const* d_in, const int* in_sizes, int n_in,
                              void* d_out, int out_size, void* d_ws, size_t ws_size,
                              hipStream_t stream) {
    const float* feats = (const float*)d_in[0];
    const int*   src   = (const int*)d_in[1];
    const int*   dst   = (const int*)d_in[2];
    const int*   gid   = (const int*)d_in[3];
    const float* W[3]  = {(const float*)d_in[4],  (const float*)d_in[8],  (const float*)d_in[12]};
    const float* b[3]  = {(const float*)d_in[5],  (const float*)d_in[9],  (const float*)d_in[13]};
    const float* R[3]  = {(const float*)d_in[6],  (const float*)d_in[10], (const float*)d_in[14]};
    const float* rb[3] = {(const float*)d_in[7],  (const float*)d_in[11], (const float*)d_in[15]};
    const float* Wm1 = (const float*)d_in[16];
    const float* bm1 = (const float*)d_in[17];
    const float* Wm2 = (const float*)d_in[18];
    const float* bm2 = (const float*)d_in[19];
    float* out = (float*)d_out;

    // workspace carve
    char* ws = (char*)d_ws;
    const size_t node_bf16 = (size_t)N_NODES * HID * sizeof(unsigned short);  // 12.8 MB
    unsigned short* xbufb     = (unsigned short*)(ws); ws += node_bf16;
    unsigned*       xq        = (unsigned*)(ws);       ws += (size_t)N_NODES * 16 * sizeof(unsigned); // 6.4 MB (2 halves)
    float*          xscale    = (float*)(ws);          ws += (size_t)N_NODES * sizeof(float);         // 400 KB
    unsigned short* resb      = (unsigned short*)(ws); ws += node_bf16;
    float*          gbuf      = (float*)(ws);          ws += (size_t)N_GRAPHS * HID * sizeof(float);
    int*            cursor    = (int*)(ws);            ws += (size_t)NBUCKET * sizeof(int);
    int*            row_start = (int*)(ws);            ws += (size_t)N_NODES * sizeof(int);
    int*            row_deg   = (int*)(ws);            ws += (size_t)N_NODES * sizeof(int);
    int*            blockHist = (int*)(ws);            ws += (size_t)NBUCKET * NBLK * sizeof(int);  // 800 KB
    unsigned short* wtbuf     = (unsigned short*)(ws); ws += (size_t)(2 * SZ0 + 4 * SZ12) * sizeof(unsigned short);
    ws = (char*)(((size_t)ws + 255) & ~(size_t)255);
    unsigned*       pairs     = (unsigned*)(ws);       ws += (size_t)NBUCKET * BUCKET_CAP * sizeof(unsigned); // 25.6 MB

    // ---- one-time weight transpose/quantize + bucketed CSR build
    prep_wt_kernel<<<6, 256, 0, stream>>>(W[0], R[0], W[1], R[1], W[2], R[2], wtbuf);
    split_hist_kernel<<<NBLK, SPLIT_THREADS, 0, stream>>>(dst, blockHist);
    split_scan_kernel<<<NBUCKET, NBLK, 0, stream>>>(blockHist, cursor);
    split_scatter_kernel<<<NBLK, SPLIT_THREADS, 0, stream>>>(src, dst, blockHist, pairs);
    bucket_sort_kernel<<<NBUCKET, 256, 0, stream>>>(pairs, cursor, row_start, row_deg);

    const unsigned short* wt_l[3] = {wtbuf, wtbuf + 2 * SZ0, wtbuf + 2 * SZ0 + 2 * SZ12};

    for (int l = 0; l < 3; ++l) {
        {
            int blocks = (N_NODES + 63) / 64;     // 64 nodes per block
            if (l == 0)
                proj_mfma_kernel<IN_DIM, 96, STRIDE0, false><<<blocks, 256, 0, stream>>>(
                    (const void*)feats, wt_l[l], rb[l], xq, xscale, resb, N_NODES);
            else
                proj_mfma_kernel<HID, 64, STRIDE12, true><<<blocks, 256, 0, stream>>>(
                    (const void*)xbufb, wt_l[l], rb[l], xq, xscale, resb, N_NODES);
        }
        {
            int blocks = (N_NODES * 64 + 255) / 256;  // one wave per node
            // pass 0: half-table 0 (3.2 MB, L2-resident), feats {0-7,16-23,32-39,48-55}
            gather_half_kernel<<<blocks, 256, 0, stream>>>(
                (const uint2*)xq, xscale, row_start, row_deg,
                pairs, b[l], resb, xbufb, 0, N_NODES);
            // pass 1: half-table 1, feats {8-15,24-31,40-47,56-63}
            gather_half_kernel<<<blocks, 256, 0, stream>>>(
                (const uint2*)(xq + (size_t)N_NODES * 8), xscale, row_start, row_deg,
                pairs, b[l], resb, xbufb, 8, N_NODES);
        }
    }

    // pooling
    {
        int threads = N_GRAPHS * 64;
        pool_gather_kernel<<<(threads + 255) / 256, 256, 0, stream>>>(xbufb, gid, gbuf, N_GRAPHS);
    }
    // MLP
    {
        int threads = N_GRAPHS * 64;
        mlp_kernel<<<(threads + 255) / 256, 256, 0, stream>>>(gbuf, Wm1, bm1, Wm2, bm2, out, N_GRAPHS);
    }
}

// Round 17
// 346.095 us; speedup vs baseline: 1.3705x; 1.3705x over previous
//
#include <hip/hip_runtime.h>

#define N_NODES 100000
#define N_EDGES 3200000
#define N_GRAPHS 4096
#define IN_DIM 74
#define HID 64
#define MLP_HID 128

#define BKT_NODES 128                 // nodes per bucket
#define NBUCKET ((N_NODES + BKT_NODES - 1) / BKT_NODES)   // 782
#define BUCKET_CAP 8192               // edges capacity per bucket (mean ~4096)
#define NBLK 256                      // split blocks (long per-bucket runs)
#define SPLIT_THREADS 1024            // fat blocks for occupancy
#define CHUNK ((N_EDGES + NBLK - 1) / NBLK)               // 12500 (N_EDGES = NBLK*CHUNK exactly)

// prep'd weight layout sizes (bf16, transposed [feat][k], padded stride)
#define STRIDE0 104                   // layer0: KPAD=96, stride 104 (208B rows, 16B-aligned)
#define STRIDE12 72                   // layers 1,2: KPAD=64, stride 72 (144B rows, 16B-aligned)
#define SZ0 (64 * STRIDE0)
#define SZ12 (64 * STRIDE12)

typedef __attribute__((ext_vector_type(8))) short bf16x8;
typedef __attribute__((ext_vector_type(4))) float f32x4;

__device__ __forceinline__ unsigned short f32_to_bf16_rne(float f) {
    unsigned u = __float_as_uint(f);
    unsigned r = (u + 0x7FFFu + ((u >> 16) & 1u)) >> 16;
    return (unsigned short)r;
}
__device__ __forceinline__ float bf16u_f(unsigned short u) {
    return __uint_as_float((unsigned)u << 16);
}

// accumulate 8 int8 feats (one uint2) scaled by s into a0..a7
#define ACC8(v, s) do { \
    a0 = fmaf((float)((int)((v).x << 24) >> 24), (s), a0); \
    a1 = fmaf((float)((int)((v).x << 16) >> 24), (s), a1); \
    a2 = fmaf((float)((int)((v).x <<  8) >> 24), (s), a2); \
    a3 = fmaf((float)((int)(v).x        >> 24), (s), a3); \
    a4 = fmaf((float)((int)((v).y << 24) >> 24), (s), a4); \
    a5 = fmaf((float)((int)((v).y << 16) >> 24), (s), a5); \
    a6 = fmaf((float)((int)((v).y <<  8) >> 24), (s), a6); \
    a7 = fmaf((float)((int)(v).y        >> 24), (s), a7); \
} while (0)

// ---- one-time weight prep: Wt[l][feat][k] = bf16(W_l[k][feat]), zero-padded.
__global__ void prep_wt_kernel(const float* __restrict__ W0, const float* __restrict__ R0,
                               const float* __restrict__ W1, const float* __restrict__ R1,
                               const float* __restrict__ W2, const float* __restrict__ R2,
                               unsigned short* __restrict__ wtbuf) {
    const float* srcs[6] = {W0, R0, W1, R1, W2, R2};
    int id = blockIdx.x;
    int l = id >> 1, isR = id & 1;
    const float* src = srcs[id];
    int IN = (l == 0) ? IN_DIM : HID;
    int STRIDE = (l == 0) ? STRIDE0 : STRIDE12;
    int base = (l == 0 ? 0 : 2 * SZ0 + (l - 1) * 2 * SZ12) + isR * (l == 0 ? SZ0 : SZ12);
    int total = 64 * STRIDE;
    for (int i = threadIdx.x; i < total; i += 256) {
        int n = i / STRIDE, k = i - n * STRIDE;
        wtbuf[base + i] = (k < IN) ? f32_to_bf16_rne(src[k * HID + n]) : 0;
    }
}

// ---- projection via MFMA: xq(i8, per-node scale) = x@W ; res(bf16) = relu(x@R+rb).
// LDS holds only the x tile; W/R B-fragments read from global (19 KB, L1-resident).
// xq row layout: dword c holds feats {c, c+16, c+32, c+48} as 4 signed bytes.
template<int IN, int KPAD, int STRIDE, bool BF16IN>
__launch_bounds__(256)
__global__ void proj_mfma_kernel(const void* __restrict__ x,
                                 const unsigned short* __restrict__ wt_layer, // W then R
                                 const float* __restrict__ rb,
                                 unsigned* __restrict__ xq,       // 16 dwords/node
                                 float* __restrict__ xscale,      // 1 f32/node
                                 unsigned short* __restrict__ resb,
                                 int n_nodes) {
    __shared__ __align__(16) unsigned short xs[64 * STRIDE];
    int n0 = blockIdx.x * 64;
    int tid = threadIdx.x;

    if (!BF16IN) {
        const float* xf = (const float*)x;
        for (int i = tid; i < 64 * STRIDE; i += 256) {
            int row = i / STRIDE, col = i - row * STRIDE;
            int n = n0 + row;
            float v = (col < IN && n < n_nodes) ? xf[(long)n * IN + col] : 0.f;
            xs[i] = f32_to_bf16_rne(v);
        }
    } else {
        const uint4* xb = (const uint4*)x;
        for (int i = tid; i < 64 * 8; i += 256) {
            int row = i >> 3, c8 = (i & 7) << 3;
            int n = n0 + row;
            uint4 v = make_uint4(0, 0, 0, 0);
            if (n < n_nodes) v = xb[(long)n * 8 + (i & 7)];
            *reinterpret_cast<uint4*>(&xs[row * STRIDE + c8]) = v;
        }
    }
    __syncthreads();

    int w = tid >> 6, lane = tid & 63;
    int nb = w * 16;
    int rc = lane & 15;        // A row / B col / D col
    int kg = lane >> 4;        // k-chunk of 8

    f32x4 accW[4], accR[4];
    #pragma unroll
    for (int fg = 0; fg < 4; ++fg) { accW[fg] = {0.f, 0.f, 0.f, 0.f}; accR[fg] = {0.f, 0.f, 0.f, 0.f}; }

    const unsigned short* wt = wt_layer;                 // [feat][k] bf16
    const unsigned short* rt = wt_layer + 64 * STRIDE;

    #pragma unroll
    for (int ks = 0; ks < KPAD / 32; ++ks) {
        int k0 = ks * 32 + kg * 8;
        bf16x8 a = *reinterpret_cast<const bf16x8*>(&xs[(nb + rc) * STRIDE + k0]);
        #pragma unroll
        for (int fg = 0; fg < 4; ++fg) {
            bf16x8 bw = *reinterpret_cast<const bf16x8*>(&wt[(fg * 16 + rc) * STRIDE + k0]);
            accW[fg] = __builtin_amdgcn_mfma_f32_16x16x32_bf16(a, bw, accW[fg], 0, 0, 0);
            bf16x8 br = *reinterpret_cast<const bf16x8*>(&rt[(fg * 16 + rc) * STRIDE + k0]);
            accR[fg] = __builtin_amdgcn_mfma_f32_16x16x32_bf16(a, br, accR[fg], 0, 0, 0);
        }
    }

    // D: col = lane&15, row = (lane>>4)*4 + reg; quarter shares the node.
    #pragma unroll
    for (int r = 0; r < 4; ++r) {
        float m = fmaxf(fmaxf(fabsf(accW[0][r]), fabsf(accW[1][r])),
                        fmaxf(fabsf(accW[2][r]), fabsf(accW[3][r])));
        m = fmaxf(m, __shfl_xor(m, 1, 64));
        m = fmaxf(m, __shfl_xor(m, 2, 64));
        m = fmaxf(m, __shfl_xor(m, 4, 64));
        m = fmaxf(m, __shfl_xor(m, 8, 64));
        float inv = (m > 0.f) ? 127.f / m : 0.f;
        int node = n0 + nb + kg * 4 + r;
        if (node < n_nodes) {
            unsigned pack = 0;
            #pragma unroll
            for (int fg = 0; fg < 4; ++fg) {
                int qv = (int)rintf(accW[fg][r] * inv);
                pack |= ((unsigned)(qv & 0xFF)) << (8 * fg);
            }
            xq[(long)node * 16 + rc] = pack;
            if (rc == 0) xscale[node] = m * (1.f / 127.f);
        }
    }
    #pragma unroll
    for (int fg = 0; fg < 4; ++fg) {
        int feat = fg * 16 + rc;
        float rbv = rb[feat];
        #pragma unroll
        for (int r = 0; r < 4; ++r) {
            int node = n0 + nb + kg * 4 + r;
            if (node < n_nodes)
                resb[(long)node * HID + feat] = f32_to_bf16_rne(fmaxf(accR[fg][r] + rbv, 0.f));
        }
    }
}

// ---- split pass 1: per-block LDS histogram of dst buckets (int4 loads)
__launch_bounds__(SPLIT_THREADS)
__global__ void split_hist_kernel(const int* __restrict__ dst,
                                  int* __restrict__ blockHist /*[NBUCKET][NBLK]*/) {
    __shared__ int h[NBUCKET];
    int blk = blockIdx.x, tid = threadIdx.x;
    for (int i = tid; i < NBUCKET; i += SPLIT_THREADS) h[i] = 0;
    __syncthreads();
    int lo = blk * CHUNK;                      // CHUNK % 4 == 0, 16B-aligned
    for (int e = lo + tid * 4; e < lo + CHUNK; e += SPLIT_THREADS * 4) {
        int4 d4 = *reinterpret_cast<const int4*>(&dst[e]);
        atomicAdd(&h[d4.x >> 7], 1);
        atomicAdd(&h[d4.y >> 7], 1);
        atomicAdd(&h[d4.z >> 7], 1);
        atomicAdd(&h[d4.w >> 7], 1);
    }
    __syncthreads();
    for (int i = tid; i < NBUCKET; i += SPLIT_THREADS)
        blockHist[i * NBLK + blk] = h[i];
}

// ---- split pass 2: per-bucket exclusive scan over the NBLK block counts.
__launch_bounds__(NBLK)
__global__ void split_scan_kernel(int* __restrict__ blockHist,
                                  int* __restrict__ cursor) {
    __shared__ int s[NBLK];
    int bkt = blockIdx.x, tid = threadIdx.x;
    int v = blockHist[bkt * NBLK + tid];
    s[tid] = v;
    __syncthreads();
    for (int off = 1; off < NBLK; off <<= 1) {
        int t = (tid >= off) ? s[tid - off] : 0;
        __syncthreads();
        s[tid] += t;
        __syncthreads();
    }
    blockHist[bkt * NBLK + tid] = bkt * BUCKET_CAP + s[tid] - v;   // exclusive
    if (tid == NBLK - 1) cursor[bkt] = bkt * BUCKET_CAP + s[tid]; // total end
}

// ---- split pass 3: scatter to exact positions (LDS cursors; int4 loads)
__launch_bounds__(SPLIT_THREADS)
__global__ void split_scatter_kernel(const int* __restrict__ src,
                                     const int* __restrict__ dst,
                                     const int* __restrict__ blockHist,
                                     unsigned* __restrict__ pairs) {
    __shared__ int cur[NBUCKET];
    int blk = blockIdx.x, tid = threadIdx.x;
    for (int i = tid; i < NBUCKET; i += SPLIT_THREADS)
        cur[i] = blockHist[i * NBLK + blk];
    __syncthreads();
    int lo = blk * CHUNK;
    for (int e = lo + tid * 4; e < lo + CHUNK; e += SPLIT_THREADS * 4) {
        int4 d4 = *reinterpret_cast<const int4*>(&dst[e]);
        int4 s4 = *reinterpret_cast<const int4*>(&src[e]);
        int p0 = atomicAdd(&cur[d4.x >> 7], 1);
        pairs[p0] = (unsigned)s4.x | ((unsigned)(d4.x & (BKT_NODES - 1)) << 17);
        int p1 = atomicAdd(&cur[d4.y >> 7], 1);
        pairs[p1] = (unsigned)s4.y | ((unsigned)(d4.y & (BKT_NODES - 1)) << 17);
        int p2 = atomicAdd(&cur[d4.z >> 7], 1);
        pairs[p2] = (unsigned)s4.z | ((unsigned)(d4.z & (BKT_NODES - 1)) << 17);
        int p3 = atomicAdd(&cur[d4.w >> 7], 1);
        pairs[p3] = (unsigned)s4.w | ((unsigned)(d4.w & (BKT_NODES - 1)) << 17);
    }
}

// ---- per-bucket LDS counting sort -> src sorted by dst_local; row_start/row_deg
__launch_bounds__(256)
__global__ void bucket_sort_kernel(unsigned* __restrict__ pairs,
                                   const int* __restrict__ cursor,
                                   int* __restrict__ row_start,
                                   int* __restrict__ row_deg) {
    __shared__ unsigned stage[BUCKET_CAP];   // 32 KB
    __shared__ int hist[BKT_NODES];
    __shared__ int offs[BKT_NODES];
    __shared__ int cur[BKT_NODES];
    int bkt = blockIdx.x;
    int tid = threadIdx.x;
    int base = bkt * BUCKET_CAP;
    int cnt = cursor[bkt] - base;

    for (int i = tid; i < BKT_NODES; i += 256) hist[i] = 0;
    __syncthreads();
    for (int e = tid; e < cnt; e += 256) {
        unsigned p = pairs[base + e];
        stage[e] = p;
        atomicAdd(&hist[p >> 17], 1);
    }
    __syncthreads();
    if (tid < BKT_NODES) offs[tid] = hist[tid];
    __syncthreads();
    for (int s = 1; s < BKT_NODES; s <<= 1) {
        int v = (tid < BKT_NODES && tid >= s) ? offs[tid - s] : 0;
        __syncthreads();
        if (tid < BKT_NODES) offs[tid] += v;
        __syncthreads();
    }
    if (tid < BKT_NODES) {
        int ex = offs[tid] - hist[tid];
        cur[tid] = ex;
        int node = bkt * BKT_NODES + tid;
        if (node < N_NODES) {
            row_start[node] = base + ex;
            row_deg[node] = hist[tid];
        }
    }
    __syncthreads();
    for (int e = tid; e < cnt; e += 256) {
        unsigned p = stage[e];
        int pos = atomicAdd(&cur[p >> 17], 1);
        pairs[base + pos] = p & 0x1FFFF;   // store src only
    }
}

// ---- gather aggregation + epilogue over i8 xq; 8 edges per step.
// Eighth-wave per edge: 8 lanes x uint2 cover one 64B row. f32 accumulate;
// shfl_xor(8,16,32) merges the 8 groups. (round-14 proven config: 64 us/layer)
__global__ void gather_kernel(const uint2* __restrict__ xq2,   // 8 uint2 per node
                              const float* __restrict__ xscale,
                              const int* __restrict__ row_start,
                              const int* __restrict__ row_deg,
                              const unsigned* __restrict__ csr_src,
                              const float* __restrict__ b,
                              const unsigned short* __restrict__ resb,
                              unsigned short* __restrict__ xoutb,
                              int n_nodes) {
    int wid = (blockIdx.x * blockDim.x + threadIdx.x) >> 6;
    int lane = threadIdx.x & 63;
    if (wid >= n_nodes) return;
    int g = lane >> 3;        // edge slot 0..7
    int c2 = lane & 7;        // uint2 index within row
    int start = row_start[wid];
    int end = start + row_deg[wid];
    float a0 = 0.f, a1 = 0.f, a2 = 0.f, a3 = 0.f;
    float a4 = 0.f, a5 = 0.f, a6 = 0.f, a7 = 0.f;
    int e = start;
    for (; e + 16 <= end; e += 16) {
        unsigned s0 = csr_src[e + g];
        unsigned s1 = csr_src[e + 8 + g];
        uint2 v0 = xq2[s0 * 8 + c2]; float c0 = xscale[s0];
        uint2 v1 = xq2[s1 * 8 + c2]; float c1 = xscale[s1];
        ACC8(v0, c0);
        ACC8(v1, c1);
    }
    for (; e + 8 <= end; e += 8) {
        unsigned s = csr_src[e + g];
        uint2 v = xq2[s * 8 + c2]; float cs = xscale[s];
        ACC8(v, cs);
    }
    if (e < end && g < end - e) {
        unsigned s = csr_src[e + g];
        uint2 v = xq2[s * 8 + c2]; float cs = xscale[s];
        ACC8(v, cs);
    }
    a0 += __shfl_xor(a0, 8, 64); a0 += __shfl_xor(a0, 16, 64); a0 += __shfl_xor(a0, 32, 64);
    a1 += __shfl_xor(a1, 8, 64); a1 += __shfl_xor(a1, 16, 64); a1 += __shfl_xor(a1, 32, 64);
    a2 += __shfl_xor(a2, 8, 64); a2 += __shfl_xor(a2, 16, 64); a2 += __shfl_xor(a2, 32, 64);
    a3 += __shfl_xor(a3, 8, 64); a3 += __shfl_xor(a3, 16, 64); a3 += __shfl_xor(a3, 32, 64);
    a4 += __shfl_xor(a4, 8, 64); a4 += __shfl_xor(a4, 16, 64); a4 += __shfl_xor(a4, 32, 64);
    a5 += __shfl_xor(a5, 8, 64); a5 += __shfl_xor(a5, 16, 64); a5 += __shfl_xor(a5, 32, 64);
    a6 += __shfl_xor(a6, 8, 64); a6 += __shfl_xor(a6, 16, 64); a6 += __shfl_xor(a6, 32, 64);
    a7 += __shfl_xor(a7, 8, 64); a7 += __shfl_xor(a7, 16, 64); a7 += __shfl_xor(a7, 32, 64);
    if (g == 0) {
        // dword 2*c2 -> feats {2c2, +16, +32, +48} = a0..a3
        // dword 2*c2+1 -> feats {2c2+1, +16, +32, +48} = a4..a7
        long o = (long)wid * HID;
        int f = 2 * c2;
        #pragma unroll
        for (int blk4 = 0; blk4 < 4; ++blk4) {
            int ff = f + blk4 * 16;
            float lo_a = (blk4 == 0) ? a0 : (blk4 == 1) ? a1 : (blk4 == 2) ? a2 : a3;
            float hi_a = (blk4 == 0) ? a4 : (blk4 == 1) ? a5 : (blk4 == 2) ? a6 : a7;
            float2 bv = *reinterpret_cast<const float2*>(&b[ff]);
            unsigned rv = *reinterpret_cast<const unsigned*>(&resb[o + ff]);
            float w0 = fmaxf(lo_a + bv.x, 0.f) + __uint_as_float(rv << 16);
            float w1 = fmaxf(hi_a + bv.y, 0.f) + __uint_as_float(rv & 0xFFFF0000u);
            unsigned ov = (unsigned)f32_to_bf16_rne(w0) | ((unsigned)f32_to_bf16_rne(w1) << 16);
            *reinterpret_cast<unsigned*>(&xoutb[o + ff]) = ov;
        }
    }
}

// ---- pooling gather over bf16 x: one wave/graph, binary search range
__global__ void pool_gather_kernel(const unsigned short* __restrict__ x,
                                   const int* __restrict__ gid,
                                   float* __restrict__ g,
                                   int n_graphs) {
    int wid = (blockIdx.x * blockDim.x + threadIdx.x) >> 6;
    int lane = threadIdx.x & 63;
    if (wid >= n_graphs) return;
    int lo = 0, hi = N_NODES;
    while (lo < hi) { int mid = (lo + hi) >> 1; if (gid[mid] < wid) lo = mid + 1; else hi = mid; }
    int start = lo;
    hi = N_NODES;
    while (lo < hi) { int mid = (lo + hi) >> 1; if (gid[mid] < wid + 1) lo = mid + 1; else hi = mid; }
    int end = lo;
    float acc = 0.f;
    for (int n = start; n < end; ++n)
        acc += bf16u_f(x[(long)n * HID + lane]);
    g[(long)wid * HID + lane] = acc;
}

// ---- MLP: one wave per graph. out = relu(g@Wm1+bm1) @ Wm2 + bm2
__global__ void mlp_kernel(const float* __restrict__ g,
                           const float* __restrict__ Wm1,
                           const float* __restrict__ bm1,
                           const float* __restrict__ Wm2,
                           const float* __restrict__ bm2,
                           float* __restrict__ out,
                           int n_graphs) {
    int wid = (blockIdx.x * blockDim.x + threadIdx.x) >> 6;
    int lane = threadIdx.x & 63;
    if (wid >= n_graphs) return;
    const float* gr = g + (long)wid * HID;
    float h0 = bm1[lane];
    float h1 = bm1[lane + 64];
    for (int k = 0; k < HID; ++k) {
        float gv = gr[k];
        h0 += gv * Wm1[k * MLP_HID + lane];
        h1 += gv * Wm1[k * MLP_HID + lane + 64];
    }
    float part = fmaxf(h0, 0.f) * Wm2[lane] + fmaxf(h1, 0.f) * Wm2[lane + 64];
    #pragma unroll
    for (int off = 32; off > 0; off >>= 1)
        part += __shfl_down(part, off, 64);
    if (lane == 0) out[wid] = part + bm2[0];
}

extern "C" void kernel_launch(void* const* d_in, const int* in_sizes, int n_in,
                              void* d_out, int out_size, void* d_ws, size_t ws_size,
                              hipStream_t stream) {
    const float* feats = (const float*)d_in[0];
    const int*   src   = (const int*)d_in[1];
    const int*   dst   = (const int*)d_in[2];
    const int*   gid   = (const int*)d_in[3];
    const float* W[3]  = {(const float*)d_in[4],  (const float*)d_in[8],  (const float*)d_in[12]};
    const float* b[3]  = {(const float*)d_in[5],  (const float*)d_in[9],  (const float*)d_in[13]};
    const float* R[3]  = {(const float*)d_in[6],  (const float*)d_in[10], (const float*)d_in[14]};
    const float* rb[3] = {(const float*)d_in[7],  (const float*)d_in[11], (const float*)d_in[15]};
    const float* Wm1 = (const float*)d_in[16];
    const float* bm1 = (const float*)d_in[17];
    const float* Wm2 = (const float*)d_in[18];
    const float* bm2 = (const float*)d_in[19];
    float* out = (float*)d_out;

    // workspace carve
    char* ws = (char*)d_ws;
    const size_t node_bf16 = (size_t)N_NODES * HID * sizeof(unsigned short);  // 12.8 MB
    unsigned short* xbufb     = (unsigned short*)(ws); ws += node_bf16;
    unsigned*       xq        = (unsigned*)(ws);       ws += (size_t)N_NODES * 16 * sizeof(unsigned); // 6.4 MB
    float*          xscale    = (float*)(ws);          ws += (size_t)N_NODES * sizeof(float);         // 400 KB
    unsigned short* resb      = (unsigned short*)(ws); ws += node_bf16;
    float*          gbuf      = (float*)(ws);          ws += (size_t)N_GRAPHS * HID * sizeof(float);
    int*            cursor    = (int*)(ws);            ws += (size_t)NBUCKET * sizeof(int);
    int*            row_start = (int*)(ws);            ws += (size_t)N_NODES * sizeof(int);
    int*            row_deg   = (int*)(ws);            ws += (size_t)N_NODES * sizeof(int);
    int*            blockHist = (int*)(ws);            ws += (size_t)NBUCKET * NBLK * sizeof(int);  // 800 KB
    unsigned short* wtbuf     = (unsigned short*)(ws); ws += (size_t)(2 * SZ0 + 4 * SZ12) * sizeof(unsigned short);
    ws = (char*)(((size_t)ws + 255) & ~(size_t)255);
    unsigned*       pairs     = (unsigned*)(ws);       ws += (size_t)NBUCKET * BUCKET_CAP * sizeof(unsigned); // 25.6 MB

    // ---- one-time weight transpose/quantize + bucketed CSR build
    prep_wt_kernel<<<6, 256, 0, stream>>>(W[0], R[0], W[1], R[1], W[2], R[2], wtbuf);
    split_hist_kernel<<<NBLK, SPLIT_THREADS, 0, stream>>>(dst, blockHist);
    split_scan_kernel<<<NBUCKET, NBLK, 0, stream>>>(blockHist, cursor);
    split_scatter_kernel<<<NBLK, SPLIT_THREADS, 0, stream>>>(src, dst, blockHist, pairs);
    bucket_sort_kernel<<<NBUCKET, 256, 0, stream>>>(pairs, cursor, row_start, row_deg);

    const unsigned short* wt_l[3] = {wtbuf, wtbuf + 2 * SZ0, wtbuf + 2 * SZ0 + 2 * SZ12};

    for (int l = 0; l < 3; ++l) {
        {
            int blocks = (N_NODES + 63) / 64;     // 64 nodes per block
            if (l == 0)
                proj_mfma_kernel<IN_DIM, 96, STRIDE0, false><<<blocks, 256, 0, stream>>>(
                    (const void*)feats, wt_l[l], rb[l], xq, xscale, resb, N_NODES);
            else
                proj_mfma_kernel<HID, 64, STRIDE12, true><<<blocks, 256, 0, stream>>>(
                    (const void*)xbufb, wt_l[l], rb[l], xq, xscale, resb, N_NODES);
        }
        {
            int blocks = (N_NODES * 64 + 255) / 256;  // one wave per node
            gather_kernel<<<blocks, 256, 0, stream>>>((const uint2*)xq, xscale, row_start, row_deg,
                                                      pairs, b[l], resb, xbufb, N_NODES);
        }
    }

    // pooling
    {
        int threads = N_GRAPHS * 64;
        pool_gather_kernel<<<(threads + 255) / 256, 256, 0, stream>>>(xbufb, gid, gbuf, N_GRAPHS);
    }
    // MLP
    {
        int threads = N_GRAPHS * 64;
        mlp_kernel<<<(threads + 255) / 256, 256, 0, stream>>>(gbuf, Wm1, bm1, Wm2, bm2, out, N_GRAPHS);
    }
}